// Round 2
// baseline (126.533 us; speedup 1.0000x reference)
//
#include <hip/hip_runtime.h>
#include <math.h>

// ---------------------------------------------------------------------------
// CausalKernel: out[i] = lightcone ? green(t,r) + (sum_n k_n sin(n r))/(r+1e-6)
//                                     * (sum_m tk_m cos((m+1)*0.1 t)) * e^{-0.1|t|}
//                       : 0
// Only ~9% of points are inside the future light cone -> compact, then do the
// 35937-mode sin sum with stride-8 Chebyshev recurrences, 32 mode-chunks per
// point (double-precision phase anchors per chunk; ~141 recurrence steps each
// so error stays ~1e-5 per sin).
// ---------------------------------------------------------------------------

constexpr int NCHUNK = 32;   // mode chunks per point (power of 2)

__global__ __launch_bounds__(256)
void mask_kernel(const float4* __restrict__ coords,
                 const float* __restrict__ massp,
                 const float* __restrict__ coupp,
                 const float* __restrict__ tk,
                 float* __restrict__ out,
                 int* __restrict__ counter,
                 int* __restrict__ list,
                 float* __restrict__ fw,
                 float* __restrict__ rw,
                 int N, int MT, int use_ws)
{
    int i = blockIdx.x * blockDim.x + threadIdx.x;
    if (i >= N) return;
    float4 c = coords[i];
    float t = c.x, x = c.y, y = c.z, z = c.w;
    float rsq = x * x + y * y + z * z;
    float t2  = t * t;
    bool  fl  = (t2 >= rsq) && (t >= 0.0f);          // future light cone
    float r   = sqrtf(rsq + 1e-12f);
    float g   = 0.0f;
    if (fl && (t2 > rsq) && (t > 0.0f))              // retarded Green fn region
        g = (*coupp) * expf(-(*massp) * r) / r;
    out[i] = fl ? g : 0.0f;

    if (fl && use_ws) {
        // temporal component * envelope / (r + 1e-6), computed once per point
        float tb = 0.1f * t;
        float T  = 0.0f;
        for (int m = 1; m <= MT; ++m)
            T = fmaf(tk[m - 1], cosf(tb * (float)m), T);
        T *= expf(-0.1f * fabsf(t));
        float f = T / (r + 1e-6f);
        int pos = atomicAdd(counter, 1);
        list[pos] = i;
        fw[pos]   = f;
        rw[pos]   = r;
    }
}

template <bool USE_LIST>
__global__ __launch_bounds__(256)
void mode_kernel(const float4* __restrict__ coords,
                 const float* __restrict__ ksp,
                 const float* __restrict__ tk,
                 float* __restrict__ out,
                 const int* __restrict__ counter,
                 const int* __restrict__ list,
                 const float* __restrict__ fw,
                 const float* __restrict__ rw,
                 int N, int M, int MT, int CH)
{
    int gtid   = blockIdx.x * blockDim.x + threadIdx.x;
    int wave   = gtid >> 6;
    int lane   = threadIdx.x & 63;
    int nwaves = (gridDim.x * blockDim.x) >> 6;

    int count = USE_LIST ? __builtin_amdgcn_readfirstlane(*counter) : N;
    int ngroups = (count + 63) >> 6;
    int items   = ngroups * NCHUNK;

    for (int it = wave; it < items; it += nwaves) {
        int group = __builtin_amdgcn_readfirstlane(it >> 5);  // / NCHUNK
        int chunk = __builtin_amdgcn_readfirstlane(it & (NCHUNK - 1));
        int li    = group * 64 + lane;

        float r = 0.0f, f = 0.0f;
        int   idx = 0;
        bool  act = false;
        if (li < count) {
            if (USE_LIST) {
                idx = list[li]; r = rw[li]; f = fw[li]; act = true;
            } else {
                idx = li;
                float4 c = coords[li];
                float t = c.x;
                float rsq = c.y * c.y + c.z * c.z + c.w * c.w;
                bool fl = (t * t >= rsq) && (t >= 0.0f);
                if (fl) {
                    r = sqrtf(rsq + 1e-12f);
                    float tb = 0.1f * t;
                    float T = 0.0f;
                    for (int m = 1; m <= MT; ++m)
                        T = fmaf(tk[m - 1], cosf(tb * (float)m), T);
                    T *= expf(-0.1f * fabsf(t));
                    f = T / (r + 1e-6f);
                    act = true;
                }
            }
        }

        int n0   = chunk * CH;
        if (n0 >= M) continue;
        int n_hi = min(n0 + CH, M);

        // accurate phase anchor: n0*r mod 2pi in double
        double dr = (double)r;
        float base = (float)fmod((double)n0 * dr, 6.283185307179586);
        float t2c = 2.0f * cosf(8.0f * r);   // stride-8 Chebyshev coefficient

        float sc[8], sp[8], acc[8];
#pragma unroll
        for (int j = 0; j < 8; ++j) {
            sc[j]  = sinf(fmaf((float)j,        r, base));  // sin((n0+j) r)
            sp[j]  = sinf(fmaf((float)(j - 8),  r, base));  // sin((n0+j-8) r)
            acc[j] = 0.0f;
        }

        const float* kc = ksp + n0;          // wave-uniform address
        int len   = n_hi - n0;
        int steps = len >> 3;                // groups of 8 modes
        int rem   = len & 7;

        // 2-step unrolled Chebyshev: roles of sc/sp swap each step, no movs.
        int s = 0;
        for (; s + 1 < steps; s += 2) {
            const float4 ka = *(const float4*)(kc + 8 * s);
            const float4 kb = *(const float4*)(kc + 8 * s + 4);
            const float4 kd = *(const float4*)(kc + 8 * s + 8);
            const float4 ke = *(const float4*)(kc + 8 * s + 12);
            float kv0[8] = {ka.x, ka.y, ka.z, ka.w, kb.x, kb.y, kb.z, kb.w};
            float kv1[8] = {kd.x, kd.y, kd.z, kd.w, ke.x, ke.y, ke.z, ke.w};
#pragma unroll
            for (int j = 0; j < 8; ++j) {
                acc[j] = fmaf(kv0[j], sc[j], acc[j]);
                sp[j]  = fmaf(t2c, sc[j], -sp[j]);   // sp <- sin((n+8) r)
            }
#pragma unroll
            for (int j = 0; j < 8; ++j) {
                acc[j] = fmaf(kv1[j], sp[j], acc[j]);
                sc[j]  = fmaf(t2c, sp[j], -sc[j]);   // sc <- sin((n+16) r)
            }
        }
        if (s < steps) {                      // odd leftover full step
            const float4 ka = *(const float4*)(kc + 8 * s);
            const float4 kb = *(const float4*)(kc + 8 * s + 4);
            float kv0[8] = {ka.x, ka.y, ka.z, ka.w, kb.x, kb.y, kb.z, kb.w};
#pragma unroll
            for (int j = 0; j < 8; ++j) {
                acc[j] = fmaf(kv0[j], sc[j], acc[j]);
                sp[j]  = fmaf(t2c, sc[j], -sp[j]);
            }
            // after this, "current" values live in sp
#pragma unroll
            for (int j = 0; j < 8; ++j) {
                float tmp = sc[j]; sc[j] = sp[j]; sp[j] = tmp;
            }
        }
        if (rem) {
#pragma unroll
            for (int j = 0; j < 8; ++j)
                if (j < rem)
                    acc[j] = fmaf(kc[8 * steps + j], sc[j], acc[j]);
        }

        float S = ((acc[0] + acc[1]) + (acc[2] + acc[3])) +
                  ((acc[4] + acc[5]) + (acc[6] + acc[7]));
        if (act)
            atomicAdd(&out[idx], S * f);
    }
}

extern "C" void kernel_launch(void* const* d_in, const int* in_sizes, int n_in,
                              void* d_out, int out_size, void* d_ws, size_t ws_size,
                              hipStream_t stream)
{
    const float4* coords = (const float4*)d_in[0];
    const float*  ksp    = (const float*)d_in[1];
    const float*  tk     = (const float*)d_in[2];
    const float*  massp  = (const float*)d_in[3];
    const float*  coupp  = (const float*)d_in[4];
    float*        out    = (float*)d_out;

    int N  = in_sizes[0] / 4;
    int M  = in_sizes[1];
    int MT = in_sizes[2];

    size_t needed = 16 + (size_t)N * 4 * 3;   // counter + list + fw + rw
    bool use_ws = (ws_size >= needed);

    int*   counter = (int*)d_ws;
    int*   list    = (int*)((char*)d_ws + 16);
    float* fw      = (float*)((char*)d_ws + 16 + (size_t)N * 4);
    float* rw      = (float*)((char*)d_ws + 16 + (size_t)N * 8);

    if (use_ws)
        hipMemsetAsync(d_ws, 0, 16, stream);

    mask_kernel<<<(N + 255) / 256, 256, 0, stream>>>(
        coords, massp, coupp, tk, out, counter, list, fw, rw, N, MT, use_ws ? 1 : 0);

    // chunk length: ceil(M / (NCHUNK*8)) * 8  -> multiple of 8 for float4 loads
    int CH = ((M + NCHUNK * 8 - 1) / (NCHUNK * 8)) * 8;

    if (use_ws)
        mode_kernel<true><<<2048, 256, 0, stream>>>(
            coords, ksp, tk, out, counter, list, fw, rw, N, M, MT, CH);
    else
        mode_kernel<false><<<2048, 256, 0, stream>>>(
            coords, ksp, tk, out, counter, list, fw, rw, N, M, MT, CH);
}

// Round 5
// 123.700 us; speedup vs baseline: 1.0229x; 1.0229x over previous
//
#include <hip/hip_runtime.h>
#include <math.h>

// ---------------------------------------------------------------------------
// CausalKernel. Structure:
//   mask_kernel: light-cone mask + Green term for all N points; compacts the
//     ~9% active points (wave-aggregated atomic) with f = temporal*env/(r+1e-6);
//     also builds a zero-padded copy of the spatial kernel table in ws.
//   mode_kernel: one wave per (64-point group x mode-chunk). 64 chunks of 576
//     modes; stride-8 Chebyshev sin recurrence (2 FMA/mode), double-precision
//     phase anchor per chunk, guard-free inner loop on the padded k table with
//     one-double-step prefetch distance.
// ---------------------------------------------------------------------------

constexpr int NCHUNK = 64;               // mode chunks per point (power of 2)
constexpr int CH     = 576;              // modes per chunk (mult of 16); 64*576=36864>=35937
constexpr int MPAD   = NCHUNK * CH + 64; // padded k table incl. prefetch overrun

__global__ __launch_bounds__(256)
void mask_kernel(const float4* __restrict__ coords,
                 const float* __restrict__ massp,
                 const float* __restrict__ coupp,
                 const float* __restrict__ tk,
                 const float* __restrict__ ksp,
                 float* __restrict__ out,
                 int* __restrict__ counter,
                 int* __restrict__ list,
                 float* __restrict__ fw,
                 float* __restrict__ rw,
                 float* __restrict__ kpad,
                 int N, int M, int MT)
{
    int i = blockIdx.x * blockDim.x + threadIdx.x;

    if (i < MPAD) kpad[i] = (i < M) ? ksp[i] : 0.0f;   // padded k table
    if (i >= N) return;

    float4 c = coords[i];
    float t = c.x;
    float rsq = c.y * c.y + c.z * c.z + c.w * c.w;
    float t2  = t * t;
    bool  fl  = (t2 >= rsq) && (t >= 0.0f);            // future light cone
    float r   = sqrtf(rsq + 1e-12f);
    float g   = 0.0f;
    if (fl && (t2 > rsq) && (t > 0.0f))                // retarded Green fn
        g = (*coupp) * __expf(-(*massp) * r) / r;
    out[i] = fl ? g : 0.0f;

    unsigned long long bal = __ballot(fl);
    if (fl) {
        float tb = 0.1f * t;
        float T  = 0.0f;
        for (int m = 1; m <= MT; ++m)
            T = fmaf(tk[m - 1], __cosf(tb * (float)m), T);
        T *= __expf(-0.1f * fabsf(t));
        float f = T / (r + 1e-6f);

        int lane   = threadIdx.x & 63;
        int prefix = __popcll(bal & ((1ull << lane) - 1ull));
        int base   = 0;
        if (prefix == 0)
            base = atomicAdd(counter, __popcll(bal));   // one atomic per wave
        int first = __ffsll(bal) - 1;
        base = __shfl(base, first);
        int pos = base + prefix;
        list[pos] = i;
        fw[pos]   = f;
        rw[pos]   = r;
    }
}

__global__ __launch_bounds__(256)
void mode_kernel(const float* __restrict__ kpad,
                 float* __restrict__ out,
                 const int* __restrict__ counter,
                 const int* __restrict__ list,
                 const float* __restrict__ fw,
                 const float* __restrict__ rw)
{
    int gtid   = blockIdx.x * blockDim.x + threadIdx.x;
    int wave   = gtid >> 6;
    int lane   = threadIdx.x & 63;
    int nwaves = (gridDim.x * blockDim.x) >> 6;

    int count   = __builtin_amdgcn_readfirstlane(*counter);
    int ngroups = (count + 63) >> 6;
    int items   = ngroups * NCHUNK;

    for (int it = wave; it < items; it += nwaves) {
        int group = __builtin_amdgcn_readfirstlane(it >> 6);          // / NCHUNK
        int chunk = __builtin_amdgcn_readfirstlane(it & (NCHUNK - 1));
        int li    = group * 64 + lane;

        bool  act = (li < count);
        int   idx = 0;
        float r = 0.0f, f = 0.0f;
        if (act) { idx = list[li]; r = rw[li]; f = fw[li]; }

        int n0 = chunk * CH;

        // phase anchor: base = n0*r mod 2pi, fma-based double reduction
        double y = (double)n0 * (double)r;
        double q = rint(y * 0.15915494309189535);
        float  base = (float)(y - q * 6.283185307179586);

        float t2c = 2.0f * __cosf(8.0f * r);      // stride-8 Chebyshev coeff

        float sc[8], sp[8], acc[8];
#pragma unroll
        for (int j = 0; j < 8; ++j) {
            sc[j]  = __sinf(fmaf((float)j,       r, base));   // sin((n0+j) r)
            sp[j]  = __sinf(fmaf((float)(j - 8), r, base));   // sin((n0+j-8) r)
            acc[j] = 0.0f;
        }

        const float* kc = kpad + n0;              // wave-uniform address
        float4 cA = *(const float4*)(kc);
        float4 cB = *(const float4*)(kc + 4);
        float4 cC = *(const float4*)(kc + 8);
        float4 cD = *(const float4*)(kc + 12);

        constexpr int DSTEPS = CH / 16;           // 36 guard-free double-steps
        for (int s = 0; s < DSTEPS; ++s) {
            const float* kn = kc + 16 * (s + 1);  // prefetch next double-step
            float4 nA = *(const float4*)(kn);
            float4 nB = *(const float4*)(kn + 4);
            float4 nC = *(const float4*)(kn + 8);
            float4 nD = *(const float4*)(kn + 12);

            float kv0[8] = {cA.x, cA.y, cA.z, cA.w, cB.x, cB.y, cB.z, cB.w};
            float kv1[8] = {cC.x, cC.y, cC.z, cC.w, cD.x, cD.y, cD.z, cD.w};
#pragma unroll
            for (int j = 0; j < 8; ++j) {
                acc[j] = fmaf(kv0[j], sc[j], acc[j]);
                sp[j]  = fmaf(t2c, sc[j], -sp[j]);    // sp <- sin((n+8) r)
            }
#pragma unroll
            for (int j = 0; j < 8; ++j) {
                acc[j] = fmaf(kv1[j], sp[j], acc[j]);
                sc[j]  = fmaf(t2c, sp[j], -sc[j]);    // sc <- sin((n+16) r)
            }
            cA = nA; cB = nB; cC = nC; cD = nD;
        }

        float S = ((acc[0] + acc[1]) + (acc[2] + acc[3])) +
                  ((acc[4] + acc[5]) + (acc[6] + acc[7]));
        if (act)
            atomicAdd(&out[idx], S * f);
    }
}

// Emergency fallback (ws too small / unexpected M): correct but slow.
__global__ __launch_bounds__(256)
void fallback_kernel(const float4* __restrict__ coords,
                     const float* __restrict__ ksp,
                     const float* __restrict__ tk,
                     const float* __restrict__ massp,
                     const float* __restrict__ coupp,
                     float* __restrict__ out, int N, int M, int MT)
{
    int i = blockIdx.x * blockDim.x + threadIdx.x;
    if (i >= N) return;
    float4 c = coords[i];
    float t = c.x;
    float rsq = c.y * c.y + c.z * c.z + c.w * c.w;
    float t2 = t * t;
    bool fl = (t2 >= rsq) && (t >= 0.0f);
    if (!fl) { out[i] = 0.0f; return; }
    float r = sqrtf(rsq + 1e-12f);
    float g = 0.0f;
    if ((t2 > rsq) && (t > 0.0f)) g = (*coupp) * __expf(-(*massp) * r) / r;
    float T = 0.0f, tb = 0.1f * t;
    for (int m = 1; m <= MT; ++m) T = fmaf(tk[m - 1], __cosf(tb * (float)m), T);
    T *= __expf(-0.1f * fabsf(t));
    float f = T / (r + 1e-6f);
    float S = 0.0f;
    for (int n0 = 0; n0 < M; n0 += 1024) {
        int nh = min(n0 + 1024, M);
        double y = (double)n0 * (double)r;
        double q = rint(y * 0.15915494309189535);
        float base = (float)(y - q * 6.283185307179586);
        float s0 = __sinf(base - r), s1 = __sinf(base);
        float tc = 2.0f * __cosf(r);
        for (int n = n0; n < nh; ++n) {
            S = fmaf(ksp[n], s1, S);
            float nx = fmaf(tc, s1, -s0);
            s0 = s1; s1 = nx;
        }
    }
    out[i] = g + S * f;
}

extern "C" void kernel_launch(void* const* d_in, const int* in_sizes, int n_in,
                              void* d_out, int out_size, void* d_ws, size_t ws_size,
                              hipStream_t stream)
{
    const float4* coords = (const float4*)d_in[0];
    const float*  ksp    = (const float*)d_in[1];
    const float*  tk     = (const float*)d_in[2];
    const float*  massp  = (const float*)d_in[3];
    const float*  coupp  = (const float*)d_in[4];
    float*        out    = (float*)d_out;

    int N  = in_sizes[0] / 4;
    int M  = in_sizes[1];
    int MT = in_sizes[2];

    size_t off_list = 16;
    size_t off_fw   = off_list + (size_t)N * 4;
    size_t off_rw   = off_fw   + (size_t)N * 4;
    size_t off_k    = off_rw   + (size_t)N * 4;
    size_t needed   = off_k    + (size_t)MPAD * 4;

    if (ws_size < needed || M > NCHUNK * CH) {
        fallback_kernel<<<(N + 255) / 256, 256, 0, stream>>>(
            coords, ksp, tk, massp, coupp, out, N, M, MT);
        return;
    }

    int*   counter = (int*)d_ws;
    int*   list    = (int*)((char*)d_ws + off_list);
    float* fw      = (float*)((char*)d_ws + off_fw);
    float* rw      = (float*)((char*)d_ws + off_rw);
    float* kpad    = (float*)((char*)d_ws + off_k);

    hipMemsetAsync(d_ws, 0, 16, stream);

    int nthreads = (N > MPAD) ? N : MPAD;
    mask_kernel<<<(nthreads + 255) / 256, 256, 0, stream>>>(
        coords, massp, coupp, tk, ksp, out, counter, list, fw, rw, kpad, N, M, MT);

    mode_kernel<<<2048, 256, 0, stream>>>(kpad, out, counter, list, fw, rw);
}